// Round 20
// baseline (202.281 us; speedup 1.0000x reference)
//
#include <hip/hip_runtime.h>
#include <cstdint>
#include <cstddef>

// MQA: B=2, T=2048, D=2048, H=16, HD=128. fp32 in/out, bf16 MFMA compute.
#define Bq 2
#define Tq 2048
#define Dq 2048
#define Hq 16
#define HDq 128

using f32x4  = __attribute__((ext_vector_type(4))) float;
using short8 = __attribute__((ext_vector_type(8))) short;
typedef unsigned short ushort_t;

// 1/sqrt(128) * log2(e): Q is pre-scaled by this so attention works in exp2 domain.
#define QSC 0.12751741772f

#define GLOAD_LDS16(gp, lp)                                                        \
  __builtin_amdgcn_global_load_lds((const __attribute__((address_space(1))) void*)(gp), \
                                   (__attribute__((address_space(3))) void*)(lp), 16, 0, 0)

__device__ inline ushort_t f2bf(float f) {
  uint32_t u = __float_as_uint(f);
  uint32_t r = (u + 0x7FFFu + ((u >> 16) & 1u)) >> 16;
  return (ushort_t)r;
}

// packed f32x2 -> bf16x2 (RTNE), one VALU inst
__device__ inline uint32_t cvt_pk_bf16(float a, float b) {
  uint32_t r;
  asm("v_cvt_pk_bf16_f32 %0, %1, %2" : "=v"(r) : "v"(a), "v"(b));
  return r;
}

// ---------------- fused prep: x cast (z=4,5) + 4 weight transposes (z=0..3) ----------------
__global__ __launch_bounds__(512) void prep_all(
    const float* __restrict__ x,
    const float* __restrict__ Wq, const float* __restrict__ Wk,
    const float* __restrict__ Wv, const float* __restrict__ Wo,
    ushort_t* __restrict__ xb, ushort_t* __restrict__ WqkvT, ushort_t* __restrict__ WoT) {
  const int z = blockIdx.z;
  if (z >= 4) {
    // x cast path: 2048 chunks x 1024 float4 = 4096x2048 floats.
    const int chunk = (z - 4) * 1024 + blockIdx.y * 32 + blockIdx.x;
    const int tid = threadIdx.y * 64 + threadIdx.x;  // 0..511
    const float4* src = reinterpret_cast<const float4*>(x) + (size_t)chunk * 1024;
    ushort4* dst = reinterpret_cast<ushort4*>(xb) + (size_t)chunk * 1024;
#pragma unroll
    for (int i = 0; i < 2; ++i) {
      float4 v = src[tid + i * 512];
      ushort4 u;
      u.x = f2bf(v.x); u.y = f2bf(v.y); u.z = f2bf(v.z); u.w = f2bf(v.w);
      dst[tid + i * 512] = u;
    }
    return;
  }
  const float* in;
  ushort_t* out;
  int C, row_off;
  if (z == 0)      { in = Wq; out = WqkvT; C = Dq;  row_off = 0; }
  else if (z == 1) { in = Wo; out = WoT;   C = Dq;  row_off = 0; }
  else if (z == 2) { in = Wk; out = WqkvT; C = HDq; row_off = 2048; }
  else             { in = Wv; out = WqkvT; C = HDq; row_off = 2176; }
  const int c0 = blockIdx.x * 64;
  if (c0 >= C) return;
  __shared__ float tile[64][65];
  const int r0 = blockIdx.y * 64;
  const int tx = threadIdx.x, ty = threadIdx.y;  // (64, 8)
#pragma unroll
  for (int i = ty; i < 64; i += 8)
    tile[i][tx] = in[(size_t)(r0 + i) * C + c0 + tx];
  __syncthreads();
#pragma unroll
  for (int i = ty; i < 64; i += 8)
    out[(size_t)(row_off + c0 + i) * Dq + r0 + tx] = f2bf(tile[tx][i]);
}

// ---------------- bf16 GEMM: C[M][N] = A[M][K] @ BT[N][K]^T + bias ----------------
// 128x128 tile, BK=64 (halved barrier drains), 4 waves, 3 blocks/CU. Granule swizzle
// (T2 both-sides): g ^= (row&7). XCD-chunked grid swizzle (T1).
template <int OUT_MODE>
__global__ __launch_bounds__(256, 3) void gemm_bt(
    const ushort_t* __restrict__ A, const ushort_t* __restrict__ BT,
    const float* __restrict__ bias, void* __restrict__ Cout,
    int M, int N, int K, int NXT,
    ushort_t* __restrict__ Kout, ushort_t* __restrict__ VTout,
    const float* __restrict__ bias2, const float* __restrict__ bias3) {
  constexpr int BM = 128, BN = 128, BK = 64;
  __shared__ ushort_t As[BM * BK];  // 16KB, [row][k], granule-swizzled
  __shared__ ushort_t Bs[BN * BK];  // 16KB
  const int tid = threadIdx.x;
  const int wave = tid >> 6, lane = tid & 63;
  const int wr = wave >> 1, wc = wave & 1;
  const int nwg = gridDim.x;
  const int orig = (blockIdx.x & 7) * (nwg >> 3) + (blockIdx.x >> 3);
  const int m0 = (orig / NXT) * BM, n0 = (orig % NXT) * BN;
  const int lrow = lane & 15;
  const int kswz0 = (((lane >> 4) ^ (lrow & 7)) << 3);
  const int kswz1 = (((4 + (lane >> 4)) ^ (lrow & 7)) << 3);

  int srcoff[4], dstoff[4];
#pragma unroll
  for (int p = 0; p < 4; ++p) {
    const int byteoff = p * 4096 + wave * 1024;
    const int e = (byteoff >> 1) + lane * 8;
    const int r = e >> 6, c = e & 63;
    const int cs = (((c >> 3) ^ (r & 7)) << 3);
    srcoff[p] = r * K + cs;
    dstoff[p] = byteoff;
  }

  f32x4 acc[4][4] = {};

  for (int k0 = 0; k0 < K; k0 += BK) {
#pragma unroll
    for (int p = 0; p < 4; ++p) {
      GLOAD_LDS16(A + (size_t)m0 * K + k0 + srcoff[p], (char*)As + dstoff[p]);
      GLOAD_LDS16(BT + (size_t)n0 * K + k0 + srcoff[p], (char*)Bs + dstoff[p]);
    }
    __syncthreads();
#pragma unroll
    for (int kk = 0; kk < 2; ++kk) {
      const int ksw = kk ? kswz1 : kswz0;
      short8 af[4], bfr[4];
#pragma unroll
      for (int i = 0; i < 4; ++i)
        af[i] = *(const short8*)&As[(wr * 64 + i * 16 + lrow) * BK + ksw];
#pragma unroll
      for (int i = 0; i < 4; ++i)
        bfr[i] = *(const short8*)&Bs[(wc * 64 + i * 16 + lrow) * BK + ksw];
#pragma unroll
      for (int mi = 0; mi < 4; ++mi)
#pragma unroll
        for (int ni = 0; ni < 4; ++ni)
          acc[mi][ni] = __builtin_amdgcn_mfma_f32_16x16x32_bf16(af[mi], bfr[ni], acc[mi][ni], 0, 0, 0);
    }
    __syncthreads();
  }

#pragma unroll
  for (int mi = 0; mi < 4; ++mi) {
#pragma unroll
    for (int ni = 0; ni < 4; ++ni) {
      int rbase = m0 + wr * 64 + mi * 16 + (lane >> 4) * 4;
      int col = n0 + wc * 64 + ni * 16 + lrow;
#pragma unroll
      for (int jj = 0; jj < 4; ++jj) {
        int r = rbase + jj;
        float v = acc[mi][ni][jj];
        if (OUT_MODE == 1) {
          ((float*)Cout)[(size_t)r * N + col] = v + bias[col];
        } else {
          if (col < Dq) {
            ((ushort_t*)Cout)[(size_t)r * Dq + col] = f2bf((v + bias[col]) * QSC);
          } else if (col < Dq + HDq) {
            int d = col - Dq;
            Kout[(size_t)r * HDq + d] = f2bf(v + bias2[d]);
          } else {
            int d = col - Dq - HDq;
            int b = r >> 11, t = r & (Tq - 1);
            VTout[((size_t)b * HDq + d) * Tq + t] = f2bf(v + bias3[d]);
          }
        }
      }
    }
  }
}

// ---------------- fused causal MQA attention (balanced complementary grid) ----------------
// 1024 blocks x 256 threads (4 waves x 16 q-rows = 64 rows/block); all 1024 co-resident
// (4 blocks/CU x 40KB LDS = 160KB). Balanced 4-slot mapping: slot=bid>>8, t=(bid&255)>>3,
// u=bid&7; slots {0,2} take jt=31-t, slots {1,3} take jt=t, bh=slot*8+u. Under %256
// round-robin placement each CU's 4 blocks sum to EXACTLY 66 kt-steps (vs 52..80 for
// longest-first). K/V cadence unchanged: all blocks sweep kt from 0 -> L2 stays hot.
// Phase-split single-buffer:
//   [QK reads Ks] bar1 (drains V(s)) -> issue K(s+1)  [lands under softmax+PV]
//   [PV reads Vs] bar2 (drains K(s+1)) -> issue V(s+1) [lands under next QK]
// Fixed-max softmax in exp2 domain: p = exp2(min(s,24)) (shift-invariant, exact).
__global__ __launch_bounds__(256, 4) void mqa_attn(
    const ushort_t* __restrict__ Qb, const ushort_t* __restrict__ Kb,
    const ushort_t* __restrict__ VTb, ushort_t* __restrict__ Ab) {
  const int bid = blockIdx.x;
  const int slot = bid >> 8;
  const int t = (bid & 255) >> 3, u = bid & 7;
  const int jt = (slot & 1) ? t : (31 - t);
  const int bh = slot * 8 + u;
  const int b = bh >> 4, h = bh & 15;
  const int qrow0 = jt * 64;
  const int NT = jt + 1;               // kt-steps (KVBLK=64)

  const int wave = threadIdx.x >> 6, lane = threadIdx.x & 63;
  const int lrow = lane & 15, lk8 = (lane >> 4) * 8;
  const int rb = (lane >> 4) * 4;

  __shared__ ushort_t Ks[64 * 128];   // 16KB, row t (256B), swz byte ^= ((t&7)<<4)
  __shared__ ushort_t Vs[128 * 64];   // 16KB, row d (128B), swz byte ^= ((d&7)<<4)
  __shared__ ushort_t Pl[4][16 * 64]; // 8KB, per-wave P, element-XOR swizzled

  const size_t vtb = (size_t)b * HDq * Tq;
  const size_t kbb = (size_t)b * Tq * HDq;

  // staging offsets precomputed once (4 rounds of 4KB each for K and V)
  int kgoff[4], vgoff[4], lbase[4];
#pragma unroll
  for (int rnd = 0; rnd < 4; ++rnd) {
    const int base = rnd * 4096 + wave * 1024;
    const int L = base + lane * 16;
    const int r = L >> 8, c = L & 255;
    kgoff[rnd] = r * HDq + ((c ^ ((r & 7) << 4)) >> 1);
    const int r2 = L >> 7, c2 = L & 127;
    vgoff[rnd] = r2 * Tq + ((c2 ^ ((r2 & 7) << 4)) >> 1);
    lbase[rnd] = base;
  }

  auto stageK = [&](int kt) {
    const ushort_t* kp = Kb + kbb + (size_t)kt * 64 * HDq;
#pragma unroll
    for (int rnd = 0; rnd < 4; ++rnd)
      GLOAD_LDS16(kp + kgoff[rnd], (char*)Ks + lbase[rnd]);
  };
  auto stageV = [&](int kt) {
    const ushort_t* vp = VTb + vtb + kt * 64;
#pragma unroll
    for (int rnd = 0; rnd < 4; ++rnd)
      GLOAD_LDS16(vp + vgoff[rnd], (char*)Vs + lbase[rnd]);
  };

  // Q fragments: rows qrow0 + wave*16 + lrow (Q pre-scaled by QSC)
  short8 qf[4];
  {
    const size_t qrow = (size_t)(b * Tq + qrow0 + wave * 16 + lrow) * Dq + h * HDq;
#pragma unroll
    for (int dc = 0; dc < 4; ++dc)
      qf[dc] = *(const short8*)(Qb + qrow + dc * 32 + lk8);
  }

  f32x4 o[8] = {};
  float l_run[4] = {};

  stageK(0);
  stageV(0);
  __syncthreads();  // K(0), V(0) staged (barrier drains vmcnt)

  for (int s = 0; s < NT; ++s) {
    // ---- QK^T: reads Ks only ----
    f32x4 sc[4] = {};
#pragma unroll
    for (int ni = 0; ni < 4; ++ni) {
      const int R = ni * 16 + lrow;
      short8 kf[4];
#pragma unroll
      for (int dc = 0; dc < 4; ++dc) {
        const int C = (dc * 64 + lk8 * 2) ^ ((R & 7) << 4);
        kf[dc] = *(const short8*)((const char*)Ks + R * 256 + C);
      }
#pragma unroll
      for (int dc = 0; dc < 4; ++dc)
        sc[ni] = __builtin_amdgcn_mfma_f32_16x16x32_bf16(qf[dc], kf[dc], sc[ni], 0, 0, 0);
    }

    __syncthreads();           // all waves done with Ks; drains V(s) loads
    if (s + 1 < NT) stageK(s + 1);  // lands under softmax+PV

    // ---- causal mask (diagonal step only) ----
    if (s == NT - 1) {
      const int qg = qrow0 + wave * 16 + rb;
#pragma unroll
      for (int ni = 0; ni < 4; ++ni) {
        const int kg = s * 64 + ni * 16 + lrow;
#pragma unroll
        for (int jj = 0; jj < 4; ++jj)
          if (kg > qg + jj) sc[ni][jj] = -1e30f;
      }
    }

    // ---- fixed-max softmax: p = exp2(min(s,24)); P -> swizzled per-wave LDS ----
#pragma unroll
    for (int ni = 0; ni < 4; ++ni) {
      float p0 = exp2f(fminf(sc[ni][0], 24.f));
      float p1 = exp2f(fminf(sc[ni][1], 24.f));
      float p2 = exp2f(fminf(sc[ni][2], 24.f));
      float p3 = exp2f(fminf(sc[ni][3], 24.f));
      l_run[0] += p0; l_run[1] += p1; l_run[2] += p2; l_run[3] += p3;
      const uint32_t u01 = cvt_pk_bf16(p0, p1);
      const uint32_t u23 = cvt_pk_bf16(p2, p3);
      const int col = ni * 16 + lrow;
      Pl[wave][(rb + 0) * 64 + (col ^ ((rb << 2) ^ 0))]  = (ushort_t)u01;
      Pl[wave][(rb + 1) * 64 + (col ^ ((rb << 2) ^ 8))]  = (ushort_t)(u01 >> 16);
      Pl[wave][(rb + 2) * 64 + (col ^ ((rb << 2) ^ 16))] = (ushort_t)u23;
      Pl[wave][(rb + 3) * 64 + (col ^ ((rb << 2) ^ 24))] = (ushort_t)(u23 >> 16);
    }

    // ---- PV: reads Vs only (P per-wave: same-wave ds ordering) ----
    short8 pa[2];
    const int fsw = ((lrow & 12) << 2) ^ ((lrow & 3) << 3);
#pragma unroll
    for (int kc = 0; kc < 2; ++kc)
      pa[kc] = *(const short8*)&Pl[wave][lrow * 64 + ((kc * 32 + lk8) ^ fsw)];
#pragma unroll
    for (int df = 0; df < 8; ++df) {
      const int R = df * 16 + lrow;
#pragma unroll
      for (int kc = 0; kc < 2; ++kc) {
        const int C = (kc * 64 + lk8 * 2) ^ ((R & 7) << 4);
        short8 vf = *(const short8*)((const char*)Vs + R * 128 + C);
        o[df] = __builtin_amdgcn_mfma_f32_16x16x32_bf16(pa[kc], vf, o[df], 0, 0, 0);
      }
    }

    __syncthreads();           // all waves done with Vs; drains K(s+1) loads
    if (s + 1 < NT) stageV(s + 1);  // lands under next QK
  }

  // ---- epilogue: reduce l across 16-lane column groups, normalize, write ----
  float inv[4];
#pragma unroll
  for (int jj = 0; jj < 4; ++jj) {
    float l = l_run[jj];
#pragma unroll
    for (int off = 1; off < 16; off <<= 1) l += __shfl_xor(l, off, 64);
    inv[jj] = 1.f / l;
  }
  const size_t orow = (size_t)(b * Tq + qrow0 + wave * 16 + rb);
#pragma unroll
  for (int df = 0; df < 8; ++df) {
    const int col = h * HDq + df * 16 + lrow;
#pragma unroll
    for (int jj = 0; jj < 4; ++jj)
      Ab[(orow + jj) * Dq + col] = f2bf(o[df][jj] * inv[jj]);
  }
}

// ---------------- launch ----------------
extern "C" void kernel_launch(void* const* d_in, const int* in_sizes, int n_in,
                              void* d_out, int out_size, void* d_ws, size_t ws_size,
                              hipStream_t stream) {
  const float* x  = (const float*)d_in[0];
  const float* Wq = (const float*)d_in[1];
  const float* bq = (const float*)d_in[2];
  const float* Wk = (const float*)d_in[3];
  const float* bk = (const float*)d_in[4];
  const float* Wv = (const float*)d_in[5];
  const float* bv = (const float*)d_in[6];
  const float* Wo = (const float*)d_in[7];
  const float* bo = (const float*)d_in[8];
  float* out = (float*)d_out;

  char* ws = (char*)d_ws;
  ushort_t* xb     = (ushort_t*)(ws);               // 16 MB
  ushort_t* WqkvT  = (ushort_t*)(ws + 16777216);    // 9.4 MB (2304 x 2048)
  ushort_t* WoT    = (ushort_t*)(ws + 26214400);    // 8 MB
  ushort_t* Qb     = (ushort_t*)(ws + 34603008);    // 16 MB
  ushort_t* Kb     = (ushort_t*)(ws + 51380224);    // 1 MB
  ushort_t* VTb    = (ushort_t*)(ws + 52428800);    // 1 MB
  ushort_t* Ab     = (ushort_t*)(ws + 53477376);    // 16 MB

  const int MT = Bq * Tq;  // 4096

  // fused prep: z=0..3 weight transposes, z=4..5 x cast (one dispatch, co-scheduled)
  prep_all<<<dim3(32, 32, 6), dim3(64, 8), 0, stream>>>(
      x, Wq, Wk, Wv, Wo, xb, WqkvT, WoT);

  // 1-D grids (divisible by 8) with in-kernel XCD-chunked swizzle
  gemm_bt<3><<<(2304 / 128) * (MT / 128), 256, 0, stream>>>(
      xb, WqkvT, bq, Qb, MT, 2304, Dq, 2304 / 128, Kb, VTb, bk, bv);

  mqa_attn<<<1024, 256, 0, stream>>>(Qb, Kb, VTb, Ab);

  gemm_bt<1><<<(Dq / 128) * (MT / 128), 256, 0, stream>>>(
      Ab, WoT, bo, out, MT, Dq, Dq, Dq / 128, nullptr, nullptr, nullptr, nullptr);
}

// Round 21
// 188.488 us; speedup vs baseline: 1.0732x; 1.0732x over previous
//
#include <hip/hip_runtime.h>
#include <cstdint>
#include <cstddef>

// MQA: B=2, T=2048, D=2048, H=16, HD=128. fp32 in/out, bf16 MFMA compute.
#define Bq 2
#define Tq 2048
#define Dq 2048
#define Hq 16
#define HDq 128

using f32x4  = __attribute__((ext_vector_type(4))) float;
using short8 = __attribute__((ext_vector_type(8))) short;
typedef unsigned short ushort_t;

// 1/sqrt(128) * log2(e): Q is pre-scaled by this so attention works in exp2 domain.
#define QSC 0.12751741772f

#define GLOAD_LDS16(gp, lp)                                                        \
  __builtin_amdgcn_global_load_lds((const __attribute__((address_space(1))) void*)(gp), \
                                   (__attribute__((address_space(3))) void*)(lp), 16, 0, 0)

__device__ inline ushort_t f2bf(float f) {
  uint32_t u = __float_as_uint(f);
  uint32_t r = (u + 0x7FFFu + ((u >> 16) & 1u)) >> 16;
  return (ushort_t)r;
}

// packed f32x2 -> bf16x2 (RTNE), one VALU inst
__device__ inline uint32_t cvt_pk_bf16(float a, float b) {
  uint32_t r;
  asm("v_cvt_pk_bf16_f32 %0, %1, %2" : "=v"(r) : "v"(a), "v"(b));
  return r;
}

// ---------------- fused prep: x cast (z=4,5) + 4 weight transposes (z=0..3) ----------------
__global__ __launch_bounds__(512) void prep_all(
    const float* __restrict__ x,
    const float* __restrict__ Wq, const float* __restrict__ Wk,
    const float* __restrict__ Wv, const float* __restrict__ Wo,
    ushort_t* __restrict__ xb, ushort_t* __restrict__ WqkvT, ushort_t* __restrict__ WoT) {
  const int z = blockIdx.z;
  if (z >= 4) {
    // x cast path: 2048 chunks x 1024 float4 = 4096x2048 floats.
    const int chunk = (z - 4) * 1024 + blockIdx.y * 32 + blockIdx.x;
    const int tid = threadIdx.y * 64 + threadIdx.x;  // 0..511
    const float4* src = reinterpret_cast<const float4*>(x) + (size_t)chunk * 1024;
    ushort4* dst = reinterpret_cast<ushort4*>(xb) + (size_t)chunk * 1024;
#pragma unroll
    for (int i = 0; i < 2; ++i) {
      float4 v = src[tid + i * 512];
      ushort4 u;
      u.x = f2bf(v.x); u.y = f2bf(v.y); u.z = f2bf(v.z); u.w = f2bf(v.w);
      dst[tid + i * 512] = u;
    }
    return;
  }
  const float* in;
  ushort_t* out;
  int C, row_off;
  if (z == 0)      { in = Wq; out = WqkvT; C = Dq;  row_off = 0; }
  else if (z == 1) { in = Wo; out = WoT;   C = Dq;  row_off = 0; }
  else if (z == 2) { in = Wk; out = WqkvT; C = HDq; row_off = 2048; }
  else             { in = Wv; out = WqkvT; C = HDq; row_off = 2176; }
  const int c0 = blockIdx.x * 64;
  if (c0 >= C) return;
  __shared__ float tile[64][65];
  const int r0 = blockIdx.y * 64;
  const int tx = threadIdx.x, ty = threadIdx.y;  // (64, 8)
#pragma unroll
  for (int i = ty; i < 64; i += 8)
    tile[i][tx] = in[(size_t)(r0 + i) * C + c0 + tx];
  __syncthreads();
#pragma unroll
  for (int i = ty; i < 64; i += 8)
    out[(size_t)(row_off + c0 + i) * Dq + r0 + tx] = f2bf(tile[tx][i]);
}

// ---------------- bf16 GEMM: C[M][N] = A[M][K] @ BT[N][K]^T + bias ----------------
// 128x128 tile, BK=64 (halved barrier drains), 4 waves, 3 blocks/CU. Granule swizzle
// (T2 both-sides): g ^= (row&7). XCD-chunked grid swizzle (T1).
template <int OUT_MODE>
__global__ __launch_bounds__(256, 3) void gemm_bt(
    const ushort_t* __restrict__ A, const ushort_t* __restrict__ BT,
    const float* __restrict__ bias, void* __restrict__ Cout,
    int M, int N, int K, int NXT,
    ushort_t* __restrict__ Kout, ushort_t* __restrict__ VTout,
    const float* __restrict__ bias2, const float* __restrict__ bias3) {
  constexpr int BM = 128, BN = 128, BK = 64;
  __shared__ ushort_t As[BM * BK];  // 16KB, [row][k], granule-swizzled
  __shared__ ushort_t Bs[BN * BK];  // 16KB
  const int tid = threadIdx.x;
  const int wave = tid >> 6, lane = tid & 63;
  const int wr = wave >> 1, wc = wave & 1;
  const int nwg = gridDim.x;
  const int orig = (blockIdx.x & 7) * (nwg >> 3) + (blockIdx.x >> 3);
  const int m0 = (orig / NXT) * BM, n0 = (orig % NXT) * BN;
  const int lrow = lane & 15;
  const int kswz0 = (((lane >> 4) ^ (lrow & 7)) << 3);
  const int kswz1 = (((4 + (lane >> 4)) ^ (lrow & 7)) << 3);

  int srcoff[4], dstoff[4];
#pragma unroll
  for (int p = 0; p < 4; ++p) {
    const int byteoff = p * 4096 + wave * 1024;
    const int e = (byteoff >> 1) + lane * 8;
    const int r = e >> 6, c = e & 63;
    const int cs = (((c >> 3) ^ (r & 7)) << 3);
    srcoff[p] = r * K + cs;
    dstoff[p] = byteoff;
  }

  f32x4 acc[4][4] = {};

  for (int k0 = 0; k0 < K; k0 += BK) {
#pragma unroll
    for (int p = 0; p < 4; ++p) {
      GLOAD_LDS16(A + (size_t)m0 * K + k0 + srcoff[p], (char*)As + dstoff[p]);
      GLOAD_LDS16(BT + (size_t)n0 * K + k0 + srcoff[p], (char*)Bs + dstoff[p]);
    }
    __syncthreads();
#pragma unroll
    for (int kk = 0; kk < 2; ++kk) {
      const int ksw = kk ? kswz1 : kswz0;
      short8 af[4], bfr[4];
#pragma unroll
      for (int i = 0; i < 4; ++i)
        af[i] = *(const short8*)&As[(wr * 64 + i * 16 + lrow) * BK + ksw];
#pragma unroll
      for (int i = 0; i < 4; ++i)
        bfr[i] = *(const short8*)&Bs[(wc * 64 + i * 16 + lrow) * BK + ksw];
#pragma unroll
      for (int mi = 0; mi < 4; ++mi)
#pragma unroll
        for (int ni = 0; ni < 4; ++ni)
          acc[mi][ni] = __builtin_amdgcn_mfma_f32_16x16x32_bf16(af[mi], bfr[ni], acc[mi][ni], 0, 0, 0);
    }
    __syncthreads();
  }

#pragma unroll
  for (int mi = 0; mi < 4; ++mi) {
#pragma unroll
    for (int ni = 0; ni < 4; ++ni) {
      int rbase = m0 + wr * 64 + mi * 16 + (lane >> 4) * 4;
      int col = n0 + wc * 64 + ni * 16 + lrow;
#pragma unroll
      for (int jj = 0; jj < 4; ++jj) {
        int r = rbase + jj;
        float v = acc[mi][ni][jj];
        if (OUT_MODE == 1) {
          ((float*)Cout)[(size_t)r * N + col] = v + bias[col];
        } else {
          if (col < Dq) {
            ((ushort_t*)Cout)[(size_t)r * Dq + col] = f2bf((v + bias[col]) * QSC);
          } else if (col < Dq + HDq) {
            int d = col - Dq;
            Kout[(size_t)r * HDq + d] = f2bf(v + bias2[d]);
          } else {
            int d = col - Dq - HDq;
            int b = r >> 11, t = r & (Tq - 1);
            VTout[((size_t)b * HDq + d) * Tq + t] = f2bf(v + bias3[d]);
          }
        }
      }
    }
  }
}

// ---------------- fused causal MQA attention (R19 best: longest-first, ~81us) ----------------
// 1024 blocks x 256 threads (4 waves x 16 q-rows = 64 rows/block), longest-first.
// 32 consecutive bids share one jt and sweep kt in lockstep -> each K/V tile is read by
// 32 temporally-adjacent blocks (L2 cadence invariant; R20 proved breaking it costs 15us).
// Phase-split single-buffer:
//   [QK reads Ks] bar1 (drains V(s)) -> issue K(s+1)  [lands under softmax+PV]
//   [PV reads Vs] bar2 (drains K(s+1)) -> issue V(s+1) [lands under next QK]
// LDS = 16+16+8 = 40 KB -> 4 blocks/CU. Fixed-max softmax: p = exp2(min(s,24)) (exact).
__global__ __launch_bounds__(256, 4) void mqa_attn(
    const ushort_t* __restrict__ Qb, const ushort_t* __restrict__ Kb,
    const ushort_t* __restrict__ VTb, ushort_t* __restrict__ Ab) {
  const int bid = blockIdx.x;
  const int jt = 31 - (bid >> 5);      // 64-row q-tile, longest first
  const int bh = bid & 31;
  const int b = bh >> 4, h = bh & 15;
  const int qrow0 = jt * 64;
  const int NT = jt + 1;               // kt-steps (KVBLK=64)

  const int wave = threadIdx.x >> 6, lane = threadIdx.x & 63;
  const int lrow = lane & 15, lk8 = (lane >> 4) * 8;
  const int rb = (lane >> 4) * 4;

  __shared__ ushort_t Ks[64 * 128];   // 16KB, row t (256B), swz byte ^= ((t&7)<<4)
  __shared__ ushort_t Vs[128 * 64];   // 16KB, row d (128B), swz byte ^= ((d&7)<<4)
  __shared__ ushort_t Pl[4][16 * 64]; // 8KB, per-wave P, element-XOR swizzled

  const size_t vtb = (size_t)b * HDq * Tq;
  const size_t kbb = (size_t)b * Tq * HDq;

  // staging offsets precomputed once (4 rounds of 4KB each for K and V)
  int kgoff[4], vgoff[4], lbase[4];
#pragma unroll
  for (int rnd = 0; rnd < 4; ++rnd) {
    const int base = rnd * 4096 + wave * 1024;
    const int L = base + lane * 16;
    const int r = L >> 8, c = L & 255;
    kgoff[rnd] = r * HDq + ((c ^ ((r & 7) << 4)) >> 1);
    const int r2 = L >> 7, c2 = L & 127;
    vgoff[rnd] = r2 * Tq + ((c2 ^ ((r2 & 7) << 4)) >> 1);
    lbase[rnd] = base;
  }

  auto stageK = [&](int kt) {
    const ushort_t* kp = Kb + kbb + (size_t)kt * 64 * HDq;
#pragma unroll
    for (int rnd = 0; rnd < 4; ++rnd)
      GLOAD_LDS16(kp + kgoff[rnd], (char*)Ks + lbase[rnd]);
  };
  auto stageV = [&](int kt) {
    const ushort_t* vp = VTb + vtb + kt * 64;
#pragma unroll
    for (int rnd = 0; rnd < 4; ++rnd)
      GLOAD_LDS16(vp + vgoff[rnd], (char*)Vs + lbase[rnd]);
  };

  // Q fragments: rows qrow0 + wave*16 + lrow (Q pre-scaled by QSC)
  short8 qf[4];
  {
    const size_t qrow = (size_t)(b * Tq + qrow0 + wave * 16 + lrow) * Dq + h * HDq;
#pragma unroll
    for (int dc = 0; dc < 4; ++dc)
      qf[dc] = *(const short8*)(Qb + qrow + dc * 32 + lk8);
  }

  f32x4 o[8] = {};
  float l_run[4] = {};

  stageK(0);
  stageV(0);
  __syncthreads();  // K(0), V(0) staged (barrier drains vmcnt)

  for (int s = 0; s < NT; ++s) {
    // ---- QK^T: reads Ks only ----
    f32x4 sc[4] = {};
#pragma unroll
    for (int ni = 0; ni < 4; ++ni) {
      const int R = ni * 16 + lrow;
      short8 kf[4];
#pragma unroll
      for (int dc = 0; dc < 4; ++dc) {
        const int C = (dc * 64 + lk8 * 2) ^ ((R & 7) << 4);
        kf[dc] = *(const short8*)((const char*)Ks + R * 256 + C);
      }
#pragma unroll
      for (int dc = 0; dc < 4; ++dc)
        sc[ni] = __builtin_amdgcn_mfma_f32_16x16x32_bf16(qf[dc], kf[dc], sc[ni], 0, 0, 0);
    }

    __syncthreads();           // all waves done with Ks; drains V(s) loads
    if (s + 1 < NT) stageK(s + 1);  // lands under softmax+PV

    // ---- causal mask (diagonal step only) ----
    if (s == NT - 1) {
      const int qg = qrow0 + wave * 16 + rb;
#pragma unroll
      for (int ni = 0; ni < 4; ++ni) {
        const int kg = s * 64 + ni * 16 + lrow;
#pragma unroll
        for (int jj = 0; jj < 4; ++jj)
          if (kg > qg + jj) sc[ni][jj] = -1e30f;
      }
    }

    // ---- fixed-max softmax: p = exp2(min(s,24)); P -> swizzled per-wave LDS ----
#pragma unroll
    for (int ni = 0; ni < 4; ++ni) {
      float p0 = exp2f(fminf(sc[ni][0], 24.f));
      float p1 = exp2f(fminf(sc[ni][1], 24.f));
      float p2 = exp2f(fminf(sc[ni][2], 24.f));
      float p3 = exp2f(fminf(sc[ni][3], 24.f));
      l_run[0] += p0; l_run[1] += p1; l_run[2] += p2; l_run[3] += p3;
      const uint32_t u01 = cvt_pk_bf16(p0, p1);
      const uint32_t u23 = cvt_pk_bf16(p2, p3);
      const int col = ni * 16 + lrow;
      Pl[wave][(rb + 0) * 64 + (col ^ ((rb << 2) ^ 0))]  = (ushort_t)u01;
      Pl[wave][(rb + 1) * 64 + (col ^ ((rb << 2) ^ 8))]  = (ushort_t)(u01 >> 16);
      Pl[wave][(rb + 2) * 64 + (col ^ ((rb << 2) ^ 16))] = (ushort_t)u23;
      Pl[wave][(rb + 3) * 64 + (col ^ ((rb << 2) ^ 24))] = (ushort_t)(u23 >> 16);
    }

    // ---- PV: reads Vs only (P per-wave: same-wave ds ordering) ----
    short8 pa[2];
    const int fsw = ((lrow & 12) << 2) ^ ((lrow & 3) << 3);
#pragma unroll
    for (int kc = 0; kc < 2; ++kc)
      pa[kc] = *(const short8*)&Pl[wave][lrow * 64 + ((kc * 32 + lk8) ^ fsw)];
#pragma unroll
    for (int df = 0; df < 8; ++df) {
      const int R = df * 16 + lrow;
#pragma unroll
      for (int kc = 0; kc < 2; ++kc) {
        const int C = (kc * 64 + lk8 * 2) ^ ((R & 7) << 4);
        short8 vf = *(const short8*)((const char*)Vs + R * 128 + C);
        o[df] = __builtin_amdgcn_mfma_f32_16x16x32_bf16(pa[kc], vf, o[df], 0, 0, 0);
      }
    }

    __syncthreads();           // all waves done with Vs; drains K(s+1) loads
    if (s + 1 < NT) stageV(s + 1);  // lands under next QK
  }

  // ---- epilogue: reduce l across 16-lane column groups, normalize, write ----
  float inv[4];
#pragma unroll
  for (int jj = 0; jj < 4; ++jj) {
    float l = l_run[jj];
#pragma unroll
    for (int off = 1; off < 16; off <<= 1) l += __shfl_xor(l, off, 64);
    inv[jj] = 1.f / l;
  }
  const size_t orow = (size_t)(b * Tq + qrow0 + wave * 16 + rb);
#pragma unroll
  for (int df = 0; df < 8; ++df) {
    const int col = h * HDq + df * 16 + lrow;
#pragma unroll
    for (int jj = 0; jj < 4; ++jj)
      Ab[(orow + jj) * Dq + col] = f2bf(o[df][jj] * inv[jj]);
  }
}

// ---------------- launch ----------------
extern "C" void kernel_launch(void* const* d_in, const int* in_sizes, int n_in,
                              void* d_out, int out_size, void* d_ws, size_t ws_size,
                              hipStream_t stream) {
  const float* x  = (const float*)d_in[0];
  const float* Wq = (const float*)d_in[1];
  const float* bq = (const float*)d_in[2];
  const float* Wk = (const float*)d_in[3];
  const float* bk = (const float*)d_in[4];
  const float* Wv = (const float*)d_in[5];
  const float* bv = (const float*)d_in[6];
  const float* Wo = (const float*)d_in[7];
  const float* bo = (const float*)d_in[8];
  float* out = (float*)d_out;

  char* ws = (char*)d_ws;
  ushort_t* xb     = (ushort_t*)(ws);               // 16 MB
  ushort_t* WqkvT  = (ushort_t*)(ws + 16777216);    // 9.4 MB (2304 x 2048)
  ushort_t* WoT    = (ushort_t*)(ws + 26214400);    // 8 MB
  ushort_t* Qb     = (ushort_t*)(ws + 34603008);    // 16 MB
  ushort_t* Kb     = (ushort_t*)(ws + 51380224);    // 1 MB
  ushort_t* VTb    = (ushort_t*)(ws + 52428800);    // 1 MB
  ushort_t* Ab     = (ushort_t*)(ws + 53477376);    // 16 MB

  const int MT = Bq * Tq;  // 4096

  // fused prep: z=0..3 weight transposes, z=4..5 x cast (one dispatch, co-scheduled)
  prep_all<<<dim3(32, 32, 6), dim3(64, 8), 0, stream>>>(
      x, Wq, Wk, Wv, Wo, xb, WqkvT, WoT);

  // 1-D grids (divisible by 8) with in-kernel XCD-chunked swizzle
  gemm_bt<3><<<(2304 / 128) * (MT / 128), 256, 0, stream>>>(
      xb, WqkvT, bq, Qb, MT, 2304, Dq, 2304 / 128, Kb, VTb, bk, bv);

  mqa_attn<<<1024, 256, 0, stream>>>(Qb, Kb, VTb, Ab);

  gemm_bt<1><<<(Dq / 128) * (MT / 128), 256, 0, stream>>>(
      Ab, WoT, bo, out, MT, Dq, Dq, Dq / 128, nullptr, nullptr, nullptr, nullptr);
}

// Round 22
// 187.600 us; speedup vs baseline: 1.0783x; 1.0047x over previous
//
#include <hip/hip_runtime.h>
#include <cstdint>
#include <cstddef>

// MQA: B=2, T=2048, D=2048, H=16, HD=128. fp32 in/out, bf16 MFMA compute.
#define Bq 2
#define Tq 2048
#define Dq 2048
#define Hq 16
#define HDq 128

using f32x4  = __attribute__((ext_vector_type(4))) float;
using short8 = __attribute__((ext_vector_type(8))) short;
typedef unsigned short ushort_t;

// 1/sqrt(128) * log2(e): Q is pre-scaled by this so attention works in exp2 domain.
#define QSC 0.12751741772f

#define GLOAD_LDS16(gp, lp)                                                        \
  __builtin_amdgcn_global_load_lds((const __attribute__((address_space(1))) void*)(gp), \
                                   (__attribute__((address_space(3))) void*)(lp), 16, 0, 0)

__device__ inline ushort_t f2bf(float f) {
  uint32_t u = __float_as_uint(f);
  uint32_t r = (u + 0x7FFFu + ((u >> 16) & 1u)) >> 16;
  return (ushort_t)r;
}

// packed f32x2 -> bf16x2 (RTNE), one VALU inst
__device__ inline uint32_t cvt_pk_bf16(float a, float b) {
  uint32_t r;
  asm("v_cvt_pk_bf16_f32 %0, %1, %2" : "=v"(r) : "v"(a), "v"(b));
  return r;
}

// ---------------- fused prep: x cast (z=4,5) + 4 weight transposes (z=0..3) ----------------
__global__ __launch_bounds__(512) void prep_all(
    const float* __restrict__ x,
    const float* __restrict__ Wq, const float* __restrict__ Wk,
    const float* __restrict__ Wv, const float* __restrict__ Wo,
    ushort_t* __restrict__ xb, ushort_t* __restrict__ WqkvT, ushort_t* __restrict__ WoT) {
  const int z = blockIdx.z;
  if (z >= 4) {
    // x cast path: 2048 chunks x 1024 float4 = 4096x2048 floats.
    const int chunk = (z - 4) * 1024 + blockIdx.y * 32 + blockIdx.x;
    const int tid = threadIdx.y * 64 + threadIdx.x;  // 0..511
    const float4* src = reinterpret_cast<const float4*>(x) + (size_t)chunk * 1024;
    ushort4* dst = reinterpret_cast<ushort4*>(xb) + (size_t)chunk * 1024;
#pragma unroll
    for (int i = 0; i < 2; ++i) {
      float4 v = src[tid + i * 512];
      ushort4 u;
      u.x = f2bf(v.x); u.y = f2bf(v.y); u.z = f2bf(v.z); u.w = f2bf(v.w);
      dst[tid + i * 512] = u;
    }
    return;
  }
  const float* in;
  ushort_t* out;
  int C, row_off;
  if (z == 0)      { in = Wq; out = WqkvT; C = Dq;  row_off = 0; }
  else if (z == 1) { in = Wo; out = WoT;   C = Dq;  row_off = 0; }
  else if (z == 2) { in = Wk; out = WqkvT; C = HDq; row_off = 2048; }
  else             { in = Wv; out = WqkvT; C = HDq; row_off = 2176; }
  const int c0 = blockIdx.x * 64;
  if (c0 >= C) return;
  __shared__ float tile[64][65];
  const int r0 = blockIdx.y * 64;
  const int tx = threadIdx.x, ty = threadIdx.y;  // (64, 8)
#pragma unroll
  for (int i = ty; i < 64; i += 8)
    tile[i][tx] = in[(size_t)(r0 + i) * C + c0 + tx];
  __syncthreads();
#pragma unroll
  for (int i = ty; i < 64; i += 8)
    out[(size_t)(row_off + c0 + i) * Dq + r0 + tx] = f2bf(tile[tx][i]);
}

// ---------------- bf16 GEMM: C[M][N] = A[M][K] @ BT[N][K]^T + bias ----------------
// 128x128 tile, BK=64 (halved barrier drains), 4 waves, 3 blocks/CU. Granule swizzle
// (T2 both-sides): g ^= (row&7). XCD-chunked grid swizzle (T1).
template <int OUT_MODE>
__global__ __launch_bounds__(256, 3) void gemm_bt(
    const ushort_t* __restrict__ A, const ushort_t* __restrict__ BT,
    const float* __restrict__ bias, void* __restrict__ Cout,
    int M, int N, int K, int NXT,
    ushort_t* __restrict__ Kout, ushort_t* __restrict__ VTout,
    const float* __restrict__ bias2, const float* __restrict__ bias3) {
  constexpr int BM = 128, BN = 128, BK = 64;
  __shared__ ushort_t As[BM * BK];  // 16KB, [row][k], granule-swizzled
  __shared__ ushort_t Bs[BN * BK];  // 16KB
  const int tid = threadIdx.x;
  const int wave = tid >> 6, lane = tid & 63;
  const int wr = wave >> 1, wc = wave & 1;
  const int nwg = gridDim.x;
  const int orig = (blockIdx.x & 7) * (nwg >> 3) + (blockIdx.x >> 3);
  const int m0 = (orig / NXT) * BM, n0 = (orig % NXT) * BN;
  const int lrow = lane & 15;
  const int kswz0 = (((lane >> 4) ^ (lrow & 7)) << 3);
  const int kswz1 = (((4 + (lane >> 4)) ^ (lrow & 7)) << 3);

  int srcoff[4], dstoff[4];
#pragma unroll
  for (int p = 0; p < 4; ++p) {
    const int byteoff = p * 4096 + wave * 1024;
    const int e = (byteoff >> 1) + lane * 8;
    const int r = e >> 6, c = e & 63;
    const int cs = (((c >> 3) ^ (r & 7)) << 3);
    srcoff[p] = r * K + cs;
    dstoff[p] = byteoff;
  }

  f32x4 acc[4][4] = {};

  for (int k0 = 0; k0 < K; k0 += BK) {
#pragma unroll
    for (int p = 0; p < 4; ++p) {
      GLOAD_LDS16(A + (size_t)m0 * K + k0 + srcoff[p], (char*)As + dstoff[p]);
      GLOAD_LDS16(BT + (size_t)n0 * K + k0 + srcoff[p], (char*)Bs + dstoff[p]);
    }
    __syncthreads();
#pragma unroll
    for (int kk = 0; kk < 2; ++kk) {
      const int ksw = kk ? kswz1 : kswz0;
      short8 af[4], bfr[4];
#pragma unroll
      for (int i = 0; i < 4; ++i)
        af[i] = *(const short8*)&As[(wr * 64 + i * 16 + lrow) * BK + ksw];
#pragma unroll
      for (int i = 0; i < 4; ++i)
        bfr[i] = *(const short8*)&Bs[(wc * 64 + i * 16 + lrow) * BK + ksw];
#pragma unroll
      for (int mi = 0; mi < 4; ++mi)
#pragma unroll
        for (int ni = 0; ni < 4; ++ni)
          acc[mi][ni] = __builtin_amdgcn_mfma_f32_16x16x32_bf16(af[mi], bfr[ni], acc[mi][ni], 0, 0, 0);
    }
    __syncthreads();
  }

#pragma unroll
  for (int mi = 0; mi < 4; ++mi) {
#pragma unroll
    for (int ni = 0; ni < 4; ++ni) {
      int rbase = m0 + wr * 64 + mi * 16 + (lane >> 4) * 4;
      int col = n0 + wc * 64 + ni * 16 + lrow;
#pragma unroll
      for (int jj = 0; jj < 4; ++jj) {
        int r = rbase + jj;
        float v = acc[mi][ni][jj];
        if (OUT_MODE == 1) {
          ((float*)Cout)[(size_t)r * N + col] = v + bias[col];
        } else {
          if (col < Dq) {
            ((ushort_t*)Cout)[(size_t)r * Dq + col] = f2bf((v + bias[col]) * QSC);
          } else if (col < Dq + HDq) {
            int d = col - Dq;
            Kout[(size_t)r * HDq + d] = f2bf(v + bias2[d]);
          } else {
            int d = col - Dq - HDq;
            int b = r >> 11, t = r & (Tq - 1);
            VTout[((size_t)b * HDq + d) * Tq + t] = f2bf(v + bias3[d]);
          }
        }
      }
    }
  }
}

// ---------------- fused causal MQA attention (balanced group-jt permutation) ----------------
// 1024 blocks x 256 threads (4 waves x 16 q-rows = 64 rows/block). Identical to the
// proven R19 build EXCEPT the group->jt map: g=bid>>5 (32-wide same-jt adjacent runs
// and bh=bid&31 preserved -> K/V reader grouping and write streams unchanged; all
// blocks sweep kt from 0 in lockstep -> L2 cadence unchanged).
//   g 0..7   -> jt = 31-g   (longest, as before)
//   g 8..15  -> jt = g-8
//   g 16..23 -> jt = 39-g
//   g 24..31 -> jt = g-16
// Bijective. Under mod-256 round-robin placement (R4-verified) CU c holds groups
// {G,G+8,G+16,G+24} -> jt-sum (31-G)+G+(23-G)+(G+8)=62 -> EXACTLY 66 steps/CU
// (longest-first gave 52..80 -> 80-step makespan).
// Phase-split single-buffer:
//   [QK reads Ks] bar1 (drains V(s)) -> issue K(s+1)  [lands under softmax+PV]
//   [PV reads Vs] bar2 (drains K(s+1)) -> issue V(s+1) [lands under next QK]
// LDS = 16+16+8 = 40 KB -> 4 blocks/CU. Fixed-max softmax: p = exp2(min(s,24)) (exact).
__global__ __launch_bounds__(256, 4) void mqa_attn(
    const ushort_t* __restrict__ Qb, const ushort_t* __restrict__ Kb,
    const ushort_t* __restrict__ VTb, ushort_t* __restrict__ Ab) {
  const int bid = blockIdx.x;
  const int g = bid >> 5;
  int jt;
  if (g < 8)       jt = 31 - g;
  else if (g < 16) jt = g - 8;
  else if (g < 24) jt = 39 - g;
  else             jt = g - 16;
  const int bh = bid & 31;
  const int b = bh >> 4, h = bh & 15;
  const int qrow0 = jt * 64;
  const int NT = jt + 1;               // kt-steps (KVBLK=64)

  const int wave = threadIdx.x >> 6, lane = threadIdx.x & 63;
  const int lrow = lane & 15, lk8 = (lane >> 4) * 8;
  const int rb = (lane >> 4) * 4;

  __shared__ ushort_t Ks[64 * 128];   // 16KB, row t (256B), swz byte ^= ((t&7)<<4)
  __shared__ ushort_t Vs[128 * 64];   // 16KB, row d (128B), swz byte ^= ((d&7)<<4)
  __shared__ ushort_t Pl[4][16 * 64]; // 8KB, per-wave P, element-XOR swizzled

  const size_t vtb = (size_t)b * HDq * Tq;
  const size_t kbb = (size_t)b * Tq * HDq;

  // staging offsets precomputed once (4 rounds of 4KB each for K and V)
  int kgoff[4], vgoff[4], lbase[4];
#pragma unroll
  for (int rnd = 0; rnd < 4; ++rnd) {
    const int base = rnd * 4096 + wave * 1024;
    const int L = base + lane * 16;
    const int r = L >> 8, c = L & 255;
    kgoff[rnd] = r * HDq + ((c ^ ((r & 7) << 4)) >> 1);
    const int r2 = L >> 7, c2 = L & 127;
    vgoff[rnd] = r2 * Tq + ((c2 ^ ((r2 & 7) << 4)) >> 1);
    lbase[rnd] = base;
  }

  auto stageK = [&](int kt) {
    const ushort_t* kp = Kb + kbb + (size_t)kt * 64 * HDq;
#pragma unroll
    for (int rnd = 0; rnd < 4; ++rnd)
      GLOAD_LDS16(kp + kgoff[rnd], (char*)Ks + lbase[rnd]);
  };
  auto stageV = [&](int kt) {
    const ushort_t* vp = VTb + vtb + kt * 64;
#pragma unroll
    for (int rnd = 0; rnd < 4; ++rnd)
      GLOAD_LDS16(vp + vgoff[rnd], (char*)Vs + lbase[rnd]);
  };

  // Q fragments: rows qrow0 + wave*16 + lrow (Q pre-scaled by QSC)
  short8 qf[4];
  {
    const size_t qrow = (size_t)(b * Tq + qrow0 + wave * 16 + lrow) * Dq + h * HDq;
#pragma unroll
    for (int dc = 0; dc < 4; ++dc)
      qf[dc] = *(const short8*)(Qb + qrow + dc * 32 + lk8);
  }

  f32x4 o[8] = {};
  float l_run[4] = {};

  stageK(0);
  stageV(0);
  __syncthreads();  // K(0), V(0) staged (barrier drains vmcnt)

  for (int s = 0; s < NT; ++s) {
    // ---- QK^T: reads Ks only ----
    f32x4 sc[4] = {};
#pragma unroll
    for (int ni = 0; ni < 4; ++ni) {
      const int R = ni * 16 + lrow;
      short8 kf[4];
#pragma unroll
      for (int dc = 0; dc < 4; ++dc) {
        const int C = (dc * 64 + lk8 * 2) ^ ((R & 7) << 4);
        kf[dc] = *(const short8*)((const char*)Ks + R * 256 + C);
      }
#pragma unroll
      for (int dc = 0; dc < 4; ++dc)
        sc[ni] = __builtin_amdgcn_mfma_f32_16x16x32_bf16(qf[dc], kf[dc], sc[ni], 0, 0, 0);
    }

    __syncthreads();           // all waves done with Ks; drains V(s) loads
    if (s + 1 < NT) stageK(s + 1);  // lands under softmax+PV

    // ---- causal mask (diagonal step only) ----
    if (s == NT - 1) {
      const int qg = qrow0 + wave * 16 + rb;
#pragma unroll
      for (int ni = 0; ni < 4; ++ni) {
        const int kg = s * 64 + ni * 16 + lrow;
#pragma unroll
        for (int jj = 0; jj < 4; ++jj)
          if (kg > qg + jj) sc[ni][jj] = -1e30f;
      }
    }

    // ---- fixed-max softmax: p = exp2(min(s,24)); P -> swizzled per-wave LDS ----
#pragma unroll
    for (int ni = 0; ni < 4; ++ni) {
      float p0 = exp2f(fminf(sc[ni][0], 24.f));
      float p1 = exp2f(fminf(sc[ni][1], 24.f));
      float p2 = exp2f(fminf(sc[ni][2], 24.f));
      float p3 = exp2f(fminf(sc[ni][3], 24.f));
      l_run[0] += p0; l_run[1] += p1; l_run[2] += p2; l_run[3] += p3;
      const uint32_t u01 = cvt_pk_bf16(p0, p1);
      const uint32_t u23 = cvt_pk_bf16(p2, p3);
      const int col = ni * 16 + lrow;
      Pl[wave][(rb + 0) * 64 + (col ^ ((rb << 2) ^ 0))]  = (ushort_t)u01;
      Pl[wave][(rb + 1) * 64 + (col ^ ((rb << 2) ^ 8))]  = (ushort_t)(u01 >> 16);
      Pl[wave][(rb + 2) * 64 + (col ^ ((rb << 2) ^ 16))] = (ushort_t)u23;
      Pl[wave][(rb + 3) * 64 + (col ^ ((rb << 2) ^ 24))] = (ushort_t)(u23 >> 16);
    }

    // ---- PV: reads Vs only (P per-wave: same-wave ds ordering) ----
    short8 pa[2];
    const int fsw = ((lrow & 12) << 2) ^ ((lrow & 3) << 3);
#pragma unroll
    for (int kc = 0; kc < 2; ++kc)
      pa[kc] = *(const short8*)&Pl[wave][lrow * 64 + ((kc * 32 + lk8) ^ fsw)];
#pragma unroll
    for (int df = 0; df < 8; ++df) {
      const int R = df * 16 + lrow;
#pragma unroll
      for (int kc = 0; kc < 2; ++kc) {
        const int C = (kc * 64 + lk8 * 2) ^ ((R & 7) << 4);
        short8 vf = *(const short8*)((const char*)Vs + R * 128 + C);
        o[df] = __builtin_amdgcn_mfma_f32_16x16x32_bf16(pa[kc], vf, o[df], 0, 0, 0);
      }
    }

    __syncthreads();           // all waves done with Vs; drains K(s+1) loads
    if (s + 1 < NT) stageV(s + 1);  // lands under next QK
  }

  // ---- epilogue: reduce l across 16-lane column groups, normalize, write ----
  float inv[4];
#pragma unroll
  for (int jj = 0; jj < 4; ++jj) {
    float l = l_run[jj];
#pragma unroll
    for (int off = 1; off < 16; off <<= 1) l += __shfl_xor(l, off, 64);
    inv[jj] = 1.f / l;
  }
  const size_t orow = (size_t)(b * Tq + qrow0 + wave * 16 + rb);
#pragma unroll
  for (int df = 0; df < 8; ++df) {
    const int col = h * HDq + df * 16 + lrow;
#pragma unroll
    for (int jj = 0; jj < 4; ++jj)
      Ab[(orow + jj) * Dq + col] = f2bf(o[df][jj] * inv[jj]);
  }
}

// ---------------- launch ----------------
extern "C" void kernel_launch(void* const* d_in, const int* in_sizes, int n_in,
                              void* d_out, int out_size, void* d_ws, size_t ws_size,
                              hipStream_t stream) {
  const float* x  = (const float*)d_in[0];
  const float* Wq = (const float*)d_in[1];
  const float* bq = (const float*)d_in[2];
  const float* Wk = (const float*)d_in[3];
  const float* bk = (const float*)d_in[4];
  const float* Wv = (const float*)d_in[5];
  const float* bv = (const float*)d_in[6];
  const float* Wo = (const float*)d_in[7];
  const float* bo = (const float*)d_in[8];
  float* out = (float*)d_out;

  char* ws = (char*)d_ws;
  ushort_t* xb     = (ushort_t*)(ws);               // 16 MB
  ushort_t* WqkvT  = (ushort_t*)(ws + 16777216);    // 9.4 MB (2304 x 2048)
  ushort_t* WoT    = (ushort_t*)(ws + 26214400);    // 8 MB
  ushort_t* Qb     = (ushort_t*)(ws + 34603008);    // 16 MB
  ushort_t* Kb     = (ushort_t*)(ws + 51380224);    // 1 MB
  ushort_t* VTb    = (ushort_t*)(ws + 52428800);    // 1 MB
  ushort_t* Ab     = (ushort_t*)(ws + 53477376);    // 16 MB

  const int MT = Bq * Tq;  // 4096

  // fused prep: z=0..3 weight transposes, z=4..5 x cast (one dispatch, co-scheduled)
  prep_all<<<dim3(32, 32, 6), dim3(64, 8), 0, stream>>>(
      x, Wq, Wk, Wv, Wo, xb, WqkvT, WoT);

  // 1-D grids (divisible by 8) with in-kernel XCD-chunked swizzle
  gemm_bt<3><<<(2304 / 128) * (MT / 128), 256, 0, stream>>>(
      xb, WqkvT, bq, Qb, MT, 2304, Dq, 2304 / 128, Kb, VTb, bk, bv);

  mqa_attn<<<1024, 256, 0, stream>>>(Qb, Kb, VTb, Ab);

  gemm_bt<1><<<(Dq / 128) * (MT / 128), 256, 0, stream>>>(
      Ab, WoT, bo, out, MT, Dq, Dq, Dq / 128, nullptr, nullptr, nullptr, nullptr);
}